// Round 1
// baseline (1105.540 us; speedup 1.0000x reference)
//
#include <hip/hip_runtime.h>
#include <math.h>

#define B 16384
#define K 1024
#define D 512
#define INV_T 14.285714285714286f   // 1/0.07

#define RPB 64      // rows per block
#define KT  128     // k tile
#define DK  32      // d chunk
#define ZSTRIDE 68  // padded LDS stride for zT (16B aligned: 68*4=272)
#define CSTRIDE 132 // padded LDS stride for cT (132*4=528, 16B aligned)

// ---------- Kernel A: csq[k] = sum_d clusters[k][d]^2 ----------
__global__ void csq_kernel(const float* __restrict__ clusters, float* __restrict__ csq) {
    int row  = blockIdx.x;       // 1024 blocks, 64 threads (one wave)
    int lane = threadIdx.x;
    const float* c = clusters + (size_t)row * D;
    float s = 0.f;
    #pragma unroll
    for (int i = 0; i < D / 64; ++i) {
        float v = c[lane + 64 * i];
        s = fmaf(v, v, s);
    }
    #pragma unroll
    for (int m = 32; m >= 1; m >>= 1) s += __shfl_xor(s, m);
    if (lane == 0) csq[row] = s;
}

// ---------- Main fused kernel ----------
// grid = 256 blocks (64 rows each), 256 threads.
// Thread grid 16(tx: cols) x 16(ty: rows); per-thread 4 rows x 8 cols.
__global__ __launch_bounds__(256)
void fused_kernel(const float* __restrict__ z, const float* __restrict__ clusters,
                  const float* __restrict__ csq, float* __restrict__ out,
                  float* __restrict__ partials) {
    __shared__ float zT[DK * ZSTRIDE];
    __shared__ float cT[DK * CSTRIDE];
    __shared__ float csqLds[K];
    __shared__ float zsqLds[RPB];
    __shared__ float invnLds[RPB];
    __shared__ float lossLds[16];

    const int tid = threadIdx.x;
    const int tx = tid & 15;
    const int ty = tid >> 4;
    const int row0 = blockIdx.x * RPB;
    const float* zblk = z + (size_t)row0 * D;

    // stage csq
    #pragma unroll
    for (int i = 0; i < K / 256; ++i) csqLds[tid + 256 * i] = csq[tid + 256 * i];

    // zsq + invnorm: 4 threads per row, each sums a contiguous 128-float chunk
    {
        int r = tid >> 2, l = tid & 3;
        const float4* zr4 = (const float4*)(zblk + (size_t)r * D + l * (D / 4));
        float s = 0.f;
        #pragma unroll
        for (int i = 0; i < D / 16; ++i) {
            float4 v = zr4[i];
            s = fmaf(v.x, v.x, s); s = fmaf(v.y, v.y, s);
            s = fmaf(v.z, v.z, s); s = fmaf(v.w, v.w, s);
        }
        s += __shfl_xor(s, 1);
        s += __shfl_xor(s, 2);
        if (l == 0) {
            zsqLds[r] = s;
            invnLds[r] = 1.0f / fmaxf(sqrtf(s), 1e-12f);
        }
    }

    // per-row running state (4 rows per thread), replicated across the 16-lane tx group
    float runMax[4], runSum[4], bsq[4], bdot[4];
    int   bk[4];
    #pragma unroll
    for (int j = 0; j < 4; ++j) {
        runMax[j] = -INFINITY; runSum[j] = 0.f;
        bsq[j] = INFINITY; bk[j] = 0; bdot[j] = 0.f;
    }

    for (int kt = 0; kt < K / KT; ++kt) {
        const int k0 = kt * KT;
        float acc[4][8];
        #pragma unroll
        for (int j = 0; j < 4; ++j)
            #pragma unroll
            for (int i = 0; i < 8; ++i) acc[j][i] = 0.f;

        for (int dc = 0; dc < D / DK; ++dc) {
            const int dbase = dc * DK;
            __syncthreads();
            // stage zT[d][r]  (64 rows x 32 d)
            #pragma unroll
            for (int i = 0; i < (RPB * DK) / 256; ++i) {
                int e = tid + 256 * i;
                int r = e >> 5, d = e & 31;
                zT[d * ZSTRIDE + r] = zblk[(size_t)r * D + dbase + d];
            }
            // stage cT[d][c]  (128 cols x 32 d)
            #pragma unroll
            for (int i = 0; i < (KT * DK) / 256; ++i) {
                int e = tid + 256 * i;
                int c = e >> 5, d = e & 31;
                cT[d * CSTRIDE + c] = clusters[(size_t)(k0 + c) * D + dbase + d];
            }
            __syncthreads();
            #pragma unroll
            for (int d = 0; d < DK; ++d) {
                float4 a  = *(const float4*)&zT[d * ZSTRIDE + ty * 4];
                float4 b0 = *(const float4*)&cT[d * CSTRIDE + tx * 8];
                float4 b1 = *(const float4*)&cT[d * CSTRIDE + tx * 8 + 4];
                float av[4] = {a.x, a.y, a.z, a.w};
                float bv[8] = {b0.x, b0.y, b0.z, b0.w, b1.x, b1.y, b1.z, b1.w};
                #pragma unroll
                for (int j = 0; j < 4; ++j)
                    #pragma unroll
                    for (int i = 0; i < 8; ++i)
                        acc[j][i] = fmaf(av[j], bv[i], acc[j][i]);
            }
        }

        // ---- per-tile epilogue: online softmax + running argmin ----
        #pragma unroll
        for (int j = 0; j < 4; ++j) {
            const int lr = ty * 4 + j;
            const float invnt = invnLds[lr] * INV_T;
            const float zsq = zsqLds[lr];

            float lg[8];
            float tmax = -INFINITY;
            #pragma unroll
            for (int i = 0; i < 8; ++i) { lg[i] = acc[j][i] * invnt; tmax = fmaxf(tmax, lg[i]); }
            #pragma unroll
            for (int m = 1; m < 16; m <<= 1) tmax = fmaxf(tmax, __shfl_xor(tmax, m));
            const float newm = fmaxf(runMax[j], tmax);
            float es = 0.f;
            #pragma unroll
            for (int i = 0; i < 8; ++i) es += __expf(lg[i] - newm);
            #pragma unroll
            for (int m = 1; m < 16; m <<= 1) es += __shfl_xor(es, m);
            runSum[j] = runSum[j] * __expf(runMax[j] - newm) + es;
            runMax[j] = newm;

            // argmin over this tile's 128 cols (first-index tie-break)
            float msq = INFINITY; int mk = 0; float md = 0.f;
            #pragma unroll
            for (int i = 0; i < 8; ++i) {
                int kk = k0 + tx * 8 + i;
                float sq = zsq + csqLds[kk] - 2.0f * acc[j][i];
                if (sq < msq) { msq = sq; mk = kk; md = acc[j][i]; }
            }
            #pragma unroll
            for (int m = 1; m < 16; m <<= 1) {
                float osq = __shfl_xor(msq, m);
                int   okk = __shfl_xor(mk, m);
                float od  = __shfl_xor(md, m);
                if (osq < msq || (osq == msq && okk < mk)) { msq = osq; mk = okk; md = od; }
            }
            if (msq < bsq[j] || (msq == bsq[j] && mk < bk[j])) { bsq[j] = msq; bk[j] = mk; bdot[j] = md; }
        }
    }

    // ---- outputs ----
    // closest (as float) + per-block loss partial
    if (tx == 0) {
        float lpart = 0.f;
        #pragma unroll
        for (int j = 0; j < 4; ++j) {
            const int lr = ty * 4 + j;
            const int grow = row0 + lr;
            out[(size_t)B * D + grow] = (float)bk[j];
            const float invnt = invnLds[lr] * INV_T;
            lpart += runMax[j] + logf(runSum[j]) - bdot[j] * invnt;
        }
        lossLds[ty] = lpart;
    }
    __syncthreads();
    if (tid == 0) {
        float s = 0.f;
        #pragma unroll
        for (int i = 0; i < 16; ++i) s += lossLds[i];
        partials[blockIdx.x] = s;
    }

    // z_n = z * invnorm  (coalesced float4 stream)
    const float4* z4 = (const float4*)zblk;
    float4* o4 = (float4*)(out + (size_t)row0 * D);
    #pragma unroll
    for (int i = 0; i < (RPB * D / 4) / 256; ++i) {
        int e = tid + 256 * i;
        int r = e >> 7;            // 128 float4 per row
        float4 v = z4[e];
        float inv = invnLds[r];
        v.x *= inv; v.y *= inv; v.z *= inv; v.w *= inv;
        o4[e] = v;
    }
}

// ---------- Final loss reduction ----------
__global__ void loss_kernel(const float* __restrict__ partials, float* __restrict__ out) {
    int tid = threadIdx.x;  // 256
    float s = partials[tid];
    #pragma unroll
    for (int m = 1; m < 64; m <<= 1) s += __shfl_xor(s, m);
    __shared__ float w[4];
    if ((tid & 63) == 0) w[tid >> 6] = s;
    __syncthreads();
    if (tid == 0) out[(size_t)B * D + B] = (w[0] + w[1] + w[2] + w[3]) * (1.0f / (float)B);
}

extern "C" void kernel_launch(void* const* d_in, const int* in_sizes, int n_in,
                              void* d_out, int out_size, void* d_ws, size_t ws_size,
                              hipStream_t stream) {
    const float* z        = (const float*)d_in[0];
    const float* clusters = (const float*)d_in[1];
    float* out = (float*)d_out;
    float* ws  = (float*)d_ws;
    float* csq      = ws;          // 1024 floats
    float* partials = ws + K;      // 256 floats

    csq_kernel<<<K, 64, 0, stream>>>(clusters, csq);
    fused_kernel<<<B / RPB, 256, 0, stream>>>(z, clusters, csq, out, partials);
    loss_kernel<<<1, 256, 0, stream>>>(partials, out);
}

// Round 2
// 395.263 us; speedup vs baseline: 2.7970x; 2.7970x over previous
//
#include <hip/hip_runtime.h>
#include <math.h>

#define B 16384
#define K 1024
#define D 512
#define INV_T 14.285714285714286f   // 1/0.07
#define THETA 0.05f
#define RPB 32                       // rows per main block

typedef __attribute__((ext_vector_type(8))) short bf16x8;
typedef __attribute__((ext_vector_type(16))) float f32x16;

typedef const __attribute__((address_space(1))) void* gas_ptr;
typedef __attribute__((address_space(3))) void* las_ptr;

__device__ __forceinline__ void async_copy16(const void* g, void* l) {
  __builtin_amdgcn_global_load_lds((gas_ptr)g, (las_ptr)l, 16, 0, 0);
}

__device__ __forceinline__ unsigned bf16rne(float x) {
  unsigned u = __float_as_uint(x);
  return (u + 0x7FFFu + ((u >> 16) & 1u)) >> 16;
}
__device__ __forceinline__ float bf16tof(unsigned h) { return __uint_as_float(h << 16); }

__device__ __forceinline__ void cvt8(const float* v, uint4& H, uint4& L) {
  unsigned h[8], l[8];
  #pragma unroll
  for (int i = 0; i < 8; ++i) {
    unsigned hb = bf16rne(v[i]);
    float lo = v[i] - bf16tof(hb);
    h[i] = hb; l[i] = bf16rne(lo);
  }
  H = make_uint4(h[0] | (h[1] << 16), h[2] | (h[3] << 16), h[4] | (h[5] << 16), h[6] | (h[7] << 16));
  L = make_uint4(l[0] | (l[1] << 16), l[2] | (l[3] << 16), l[4] | (l[5] << 16), l[6] | (l[7] << 16));
}

// ---------- pack_z: z (fp32) -> hi/lo bf16, block-tiled layout in OUT region ----------
// layout (16B chunks): [blk 512][dc 16][h 2][g 4][r 32]; chunk content = z[blk*32+r][dc*32+g*8 .. +8]
__global__ __launch_bounds__(256) void pack_z(const float* __restrict__ z, uint4* __restrict__ zpack) {
  const int blk = blockIdx.x, t = threadIdx.x;
  #pragma unroll
  for (int i = 0; i < 8; ++i) {
    int idx = t + 256 * i;               // 0..2047
    int r = idx & 31, g = (idx >> 5) & 3, dc = idx >> 7;
    const float* src = z + ((size_t)blk * 32 + r) * D + dc * 32 + g * 8;
    float4 a = ((const float4*)src)[0], b2 = ((const float4*)src)[1];
    float v[8] = {a.x, a.y, a.z, a.w, b2.x, b2.y, b2.z, b2.w};
    uint4 H, L; cvt8(v, H, L);
    size_t base = ((size_t)blk * 16 + dc) * 256;
    zpack[base + (0 * 4 + g) * 32 + r] = H;
    zpack[base + (4 + g) * 32 + r]     = L;
  }
}

// ---------- pack_c: clusters -> hi/lo bf16 in ws + csq ----------
// layout (16B chunks): [dc 16][h 2][g 4][n 1024]
__global__ __launch_bounds__(64) void pack_c(const float* __restrict__ clusters, uint4* __restrict__ cpack,
                                             float* __restrict__ csq, float* __restrict__ lossDelta) {
  const int n = blockIdx.x, t = threadIdx.x;
  const int dc = t >> 2, g = t & 3;
  const float* src = clusters + (size_t)n * D + dc * 32 + g * 8;
  float4 a = ((const float4*)src)[0], b2 = ((const float4*)src)[1];
  float v[8] = {a.x, a.y, a.z, a.w, b2.x, b2.y, b2.z, b2.w};
  uint4 H, L; cvt8(v, H, L);
  cpack[((size_t)(dc * 2 + 0) * 4 + g) * 1024 + n] = H;
  cpack[((size_t)(dc * 2 + 1) * 4 + g) * 1024 + n] = L;
  float sq = 0.f;
  #pragma unroll
  for (int i = 0; i < 8; ++i) sq = fmaf(v[i], v[i], sq);
  #pragma unroll
  for (int m = 32; m >= 1; m >>= 1) sq += __shfl_xor(sq, m);
  if (t == 0) csq[n] = sq;
  if (n == 0 && t == 0) *lossDelta = 0.f;
}

// ---------- main fused kernel ----------
// 512 blocks x 256 thr (4 waves). Block: 32 rows x all 1024 cols.
// N-tile 256 (4 tiles); wave wid owns 64 cols of the tile; d-chunks of 32.
__global__ __launch_bounds__(256) void fused_main(
    const float* __restrict__ z, const char* zpack, const char* __restrict__ cpack,
    const float* __restrict__ csq, float* out, float* __restrict__ partials,
    int* __restrict__ wsFlag, float* __restrict__ wsBdot, float* __restrict__ wsInvnt) {
  __shared__ __align__(16) unsigned short As[2 * 4 * 32 * 8];   // 4 KB  [h][g][r][8]
  __shared__ __align__(16) unsigned short Bs[2 * 4 * 256 * 8];  // 32 KB [h][g][n][8]
  __shared__ float csqLds[K];
  __shared__ float invnL[RPB];
  __shared__ float mrg[4][RPB][6];
  __shared__ float runM[RPB], runS[RPB], rS1[RPB], rK1[RPB], rD1[RPB], rS2[RPB];

  const int tid = threadIdx.x;
  const int wid = tid >> 6;       // wave id = wc (0..3)
  const int lane = tid & 63;
  const int h2 = lane >> 5;
  const int c5 = lane & 31;
  const int blk = blockIdx.x;
  const int row0 = blk * RPB;

  #pragma unroll
  for (int i = 0; i < 4; ++i) csqLds[tid + 256 * i] = csq[tid + 256 * i];
  {
    int r = tid >> 3, l = tid & 7;
    const float4* zr = (const float4*)(z + (size_t)(row0 + r) * D + l * 64);
    float s = 0.f;
    #pragma unroll
    for (int i = 0; i < 16; ++i) {
      float4 v = zr[i];
      s = fmaf(v.x, v.x, s); s = fmaf(v.y, v.y, s);
      s = fmaf(v.z, v.z, s); s = fmaf(v.w, v.w, s);
    }
    s += __shfl_xor(s, 1); s += __shfl_xor(s, 2); s += __shfl_xor(s, 4);
    if (l == 0) invnL[r] = 1.0f / fmaxf(sqrtf(s), 1e-12f);
  }
  if (tid < RPB) {
    runM[tid] = -INFINITY; runS[tid] = 0.f;
    rS1[tid] = INFINITY; rK1[tid] = 0.f; rD1[tid] = 0.f; rS2[tid] = INFINITY;
  }

  for (int nt = 0; nt < 4; ++nt) {
    f32x16 acc0, acc1;
    #pragma unroll
    for (int i = 0; i < 16; ++i) { acc0[i] = 0.f; acc1[i] = 0.f; }

    for (int dc = 0; dc < 16; ++dc) {
      __syncthreads();
      // A: 4KB total, 1KB per wave (linear -> [h][g][r] chunks)
      async_copy16(zpack + (((size_t)blk * 16 + dc) * 4096) + wid * 1024 + (size_t)lane * 16,
                   (void*)&As[wid * 512]);
      // B: 32KB total, 8x1KB per wave
      #pragma unroll
      for (int q2 = 0; q2 < 8; ++q2) {
        int c = wid * 8 + q2; int h = c >> 4, g = (c >> 2) & 3, q = c & 3;
        async_copy16(cpack + ((((size_t)(dc * 2 + h) * 4 + g) * 1024) + nt * 256 + q * 64) * 16 + (size_t)lane * 16,
                     (void*)&Bs[((h * 4 + g) * 256 + q * 64) * 8]);
      }
      __syncthreads();
      #pragma unroll
      for (int ks = 0; ks < 2; ++ks) {
        const int g0 = ks * 2 + h2;
        bf16x8 ah  = *(const bf16x8*)&As[((0 + g0) * 32 + c5) * 8];
        bf16x8 al  = *(const bf16x8*)&As[((4 + g0) * 32 + c5) * 8];
        bf16x8 bh0 = *(const bf16x8*)&Bs[((0 + g0) * 256 + wid * 64 + c5) * 8];
        bf16x8 bl0 = *(const bf16x8*)&Bs[((4 + g0) * 256 + wid * 64 + c5) * 8];
        bf16x8 bh1 = *(const bf16x8*)&Bs[((0 + g0) * 256 + wid * 64 + 32 + c5) * 8];
        bf16x8 bl1 = *(const bf16x8*)&Bs[((4 + g0) * 256 + wid * 64 + 32 + c5) * 8];
        acc0 = __builtin_amdgcn_mfma_f32_32x32x16_bf16(ah, bh0, acc0, 0, 0, 0);
        acc0 = __builtin_amdgcn_mfma_f32_32x32x16_bf16(ah, bl0, acc0, 0, 0, 0);
        acc0 = __builtin_amdgcn_mfma_f32_32x32x16_bf16(al, bh0, acc0, 0, 0, 0);
        acc1 = __builtin_amdgcn_mfma_f32_32x32x16_bf16(ah, bh1, acc1, 0, 0, 0);
        acc1 = __builtin_amdgcn_mfma_f32_32x32x16_bf16(ah, bl1, acc1, 0, 0, 0);
        acc1 = __builtin_amdgcn_mfma_f32_32x32x16_bf16(al, bh1, acc1, 0, 0, 0);
      }
    }

    // ---- per-N-tile epilogue ----
    const int colbase = nt * 256 + wid * 64 + c5;
    #pragma unroll
    for (int reg = 0; reg < 16; ++reg) {
      const int rloc = (reg & 3) + 8 * (reg >> 2) + 4 * h2;  // C/D row mapping (m74/m101)
      float v0 = acc0[reg], v1 = acc1[reg];
      float invnt = invnL[rloc] * INV_T;
      float l0 = v0 * invnt, l1 = v1 * invnt;
      float m = fmaxf(l0, l1);
      #pragma unroll
      for (int mk = 1; mk < 32; mk <<= 1) m = fmaxf(m, __shfl_xor(m, mk));
      float es = __expf(l0 - m) + __expf(l1 - m);
      #pragma unroll
      for (int mk = 1; mk < 32; mk <<= 1) es += __shfl_xor(es, mk);
      float s0 = csqLds[colbase] - 2.f * v0;
      float s1 = csqLds[colbase + 32] - 2.f * v1;
      float b1s, b1d, b2s; int b1k;
      if (s1 < s0) { b1s = s1; b1k = colbase + 32; b1d = v1; b2s = s0; }
      else         { b1s = s0; b1k = colbase;      b1d = v0; b2s = s1; }
      #pragma unroll
      for (int mk = 1; mk < 32; mk <<= 1) {
        float os = __shfl_xor(b1s, mk);
        int   ok = __shfl_xor(b1k, mk);
        float od = __shfl_xor(b1d, mk);
        float o2 = __shfl_xor(b2s, mk);
        bool oth = (os < b1s) || (os == b1s && ok < b1k);
        float loser = oth ? b1s : os;
        b2s = fminf(loser, fminf(b2s, o2));
        if (oth) { b1s = os; b1k = ok; b1d = od; }
      }
      if (c5 == reg) {
        float* q = &mrg[wid][rloc][0];
        q[0] = m; q[1] = es; q[2] = b1s; q[3] = (float)b1k; q[4] = b1d; q[5] = b2s;
      }
    }
    __syncthreads();
    if (wid == 0 && c5 < 16) {
      const int row = (c5 & 3) + 8 * (c5 >> 2) + 4 * h2;
      float rm = runM[row], rs = runS[row], r1 = rS1[row], rd = rD1[row], r2 = rS2[row];
      int rki = (int)rK1[row];
      #pragma unroll
      for (int w = 0; w < 4; ++w) {
        const float* q = &mrg[w][row][0];
        float tm = q[0], ts = q[1], t1 = q[2]; int tk = (int)q[3]; float td = q[4], t2 = q[5];
        float nm = fmaxf(rm, tm);
        rs = rs * __expf(rm - nm) + ts * __expf(tm - nm);
        rm = nm;
        bool oth = (t1 < r1) || (t1 == r1 && tk < rki);
        float loser = oth ? r1 : t1;
        r2 = fminf(loser, fminf(r2, t2));
        if (oth) { r1 = t1; rki = tk; rd = td; }
      }
      runM[row] = rm; runS[row] = rs; rS1[row] = r1; rK1[row] = (float)rki; rD1[row] = rd; rS2[row] = r2;
    }
  }
  __syncthreads();

  if (tid < RPB) {
    const int row = tid;
    float lse = runM[row] + logf(runS[row]);
    float invnt = invnL[row] * INV_T;
    int k1 = (int)rK1[row];
    float lossr = lse - rD1[row] * invnt;
    out[(size_t)B * D + row0 + row] = (float)k1;
    wsFlag[row0 + row] = (rS2[row] - rS1[row] < THETA) ? 1 : 0;
    wsBdot[row0 + row] = rD1[row];
    wsInvnt[row0 + row] = invnt;
    #pragma unroll
    for (int mk = 16; mk >= 1; mk >>= 1) lossr += __shfl_xor(lossr, mk);
    if (tid == 0) partials[blk] = lossr;
  }
  __syncthreads();

  // z_n overwrite of zpack region (this block's rows only; all reads done)
  const float4* z4 = (const float4*)(z + (size_t)row0 * D);
  float4* o4 = (float4*)(out + (size_t)row0 * D);
  #pragma unroll
  for (int i = 0; i < 16; ++i) {
    int e = tid + 256 * i;
    int r = e >> 7;
    float4 v = z4[e];
    float inv = invnL[r];
    v.x *= inv; v.y *= inv; v.z *= inv; v.w *= inv;
    o4[e] = v;
  }
}

// ---------- fixup: exact fp32 re-argmin for margin-flagged rows ----------
__global__ __launch_bounds__(256) void fixup(
    const float* __restrict__ z, const float* __restrict__ clusters, const float* __restrict__ csq,
    const int* __restrict__ wsFlag, const float* __restrict__ wsBdot, const float* __restrict__ wsInvnt,
    float* out, float* __restrict__ lossDelta) {
  __shared__ float zrow[D];
  __shared__ int nflag;
  __shared__ int rowsL[64];
  __shared__ float wS[4]; __shared__ int wK[4]; __shared__ float wD[4];
  const int tid = threadIdx.x;
  const int row0 = blockIdx.x * 64;
  if (tid == 0) nflag = 0;
  __syncthreads();
  if (tid < 64 && wsFlag[row0 + tid]) { int i = atomicAdd(&nflag, 1); rowsL[i] = row0 + tid; }
  __syncthreads();
  const int n = nflag;
  for (int f = 0; f < n; ++f) {
    const int row = rowsL[f];
    ((float2*)zrow)[tid] = ((const float2*)(z + (size_t)row * D))[tid];
    __syncthreads();
    float bs = INFINITY, bd = 0.f; int bk2 = 0;
    #pragma unroll
    for (int kk = 0; kk < 4; ++kk) {
      const int k = tid * 4 + kk;
      const float4* c4 = (const float4*)(clusters + (size_t)k * D);
      float dot = 0.f;
      #pragma unroll 16
      for (int i = 0; i < 128; ++i) {
        float4 cv = c4[i]; float4 zv = ((const float4*)zrow)[i];
        dot = fmaf(cv.x, zv.x, dot); dot = fmaf(cv.y, zv.y, dot);
        dot = fmaf(cv.z, zv.z, dot); dot = fmaf(cv.w, zv.w, dot);
      }
      float s = csq[k] - 2.f * dot;
      if (s < bs) { bs = s; bk2 = k; bd = dot; }
    }
    #pragma unroll
    for (int mk = 1; mk < 64; mk <<= 1) {
      float os = __shfl_xor(bs, mk); int ok = __shfl_xor(bk2, mk); float od = __shfl_xor(bd, mk);
      if (os < bs || (os == bs && ok < bk2)) { bs = os; bk2 = ok; bd = od; }
    }
    if ((tid & 63) == 0) { wS[tid >> 6] = bs; wK[tid >> 6] = bk2; wD[tid >> 6] = bd; }
    __syncthreads();
    if (tid == 0) {
      float fs = wS[0]; int fk = wK[0]; float fd = wD[0];
      for (int w = 1; w < 4; ++w)
        if (wS[w] < fs || (wS[w] == fs && wK[w] < fk)) { fs = wS[w]; fk = wK[w]; fd = wD[w]; }
      int oldk = (int)out[(size_t)B * D + row];
      if (fk != oldk) {
        out[(size_t)B * D + row] = (float)fk;
        atomicAdd(lossDelta, (wsBdot[row] - fd) * wsInvnt[row]);
      }
    }
    __syncthreads();
  }
}

// ---------- final loss reduction ----------
__global__ __launch_bounds__(256) void loss_final(const float* __restrict__ partials,
                                                  const float* __restrict__ lossDelta,
                                                  float* __restrict__ out) {
  int t = threadIdx.x;
  float s = partials[t] + partials[t + 256];
  #pragma unroll
  for (int mk = 1; mk < 64; mk <<= 1) s += __shfl_xor(s, mk);
  __shared__ float w[4];
  if ((t & 63) == 0) w[t >> 6] = s;
  __syncthreads();
  if (t == 0) out[(size_t)B * D + B] = (w[0] + w[1] + w[2] + w[3] + *lossDelta) * (1.0f / (float)B);
}

extern "C" void kernel_launch(void* const* d_in, const int* in_sizes, int n_in,
                              void* d_out, int out_size, void* d_ws, size_t ws_size,
                              hipStream_t stream) {
  const float* z        = (const float*)d_in[0];
  const float* clusters = (const float*)d_in[1];
  float* out = (float*)d_out;

  // ws layout (~2.3 MB): cpack 2MB | csq 4KB | partials 2KB | flags 64KB | bdot 64KB | invnt 64KB | lossDelta
  uint4* cpack    = (uint4*)d_ws;
  float* csq      = (float*)((char*)d_ws + (2u << 20));
  float* partials = csq + 1024;
  int*   wsFlag   = (int*)(partials + 512);
  float* wsBdot   = (float*)(wsFlag + B);
  float* wsInvnt  = wsBdot + B;
  float* lossDelta = wsInvnt + B;

  pack_z<<<B / RPB, 256, 0, stream>>>(z, (uint4*)d_out);
  pack_c<<<K, 64, 0, stream>>>(clusters, cpack, csq, lossDelta);
  fused_main<<<B / RPB, 256, 0, stream>>>(z, (const char*)d_out, (const char*)cpack, csq,
                                          out, partials, wsFlag, wsBdot, wsInvnt);
  fixup<<<B / 64, 256, 0, stream>>>(z, clusters, csq, wsFlag, wsBdot, wsInvnt, out, lossDelta);
  loss_final<<<1, 256, 0, stream>>>(partials, lossDelta, out);
}

// Round 3
// 359.757 us; speedup vs baseline: 3.0730x; 1.0987x over previous
//
#include <hip/hip_runtime.h>
#include <math.h>

#define B 16384
#define K 1024
#define D 512
#define INV_T 14.285714285714286f   // 1/0.07
#define THETA 0.01f
#define RPB 64                      // rows per main block
#define NSTEPS 64                   // 4 nt * 16 dc

typedef __attribute__((ext_vector_type(8))) short bf16x8;
typedef __attribute__((ext_vector_type(16))) float f32x16;

typedef const __attribute__((address_space(1))) void* gas_ptr;
typedef __attribute__((address_space(3))) void* las_ptr;

__device__ __forceinline__ void async_copy16(const void* g, void* l) {
  __builtin_amdgcn_global_load_lds((gas_ptr)g, (las_ptr)l, 16, 0, 0);
}

__device__ __forceinline__ unsigned bf16rne(float x) {
  unsigned u = __float_as_uint(x);
  return (u + 0x7FFFu + ((u >> 16) & 1u)) >> 16;
}
__device__ __forceinline__ float bf16tof(unsigned h) { return __uint_as_float(h << 16); }

__device__ __forceinline__ void cvt8(const float* v, uint4& H, uint4& L) {
  unsigned h[8], l[8];
  #pragma unroll
  for (int i = 0; i < 8; ++i) {
    unsigned hb = bf16rne(v[i]);
    float lo = v[i] - bf16tof(hb);
    h[i] = hb; l[i] = bf16rne(lo);
  }
  H = make_uint4(h[0] | (h[1] << 16), h[2] | (h[3] << 16), h[4] | (h[5] << 16), h[6] | (h[7] << 16));
  L = make_uint4(l[0] | (l[1] << 16), l[2] | (l[3] << 16), l[4] | (l[5] << 16), l[6] | (l[7] << 16));
}

// ---------- pack_z: z -> hi/lo bf16 tiled into OUT region + invn ----------
// zpack chunk layout (16B units): [blk 256][dc 16][hg 8][r 64]
// chunk (blk,dc,h*4+g,r) = bf16x8 of z[blk*64+r][dc*32+g*8 .. +8] (h=0 hi, h=1 lo)
__global__ __launch_bounds__(256) void pack_z(const float* __restrict__ z,
                                              uint4* __restrict__ zpack,
                                              float* __restrict__ invn) {
  const int blk = blockIdx.x;
  const int wid = threadIdx.x >> 6, lane = threadIdx.x & 63;
  #pragma unroll 4
  for (int it = 0; it < 16; ++it) {
    const int r = wid * 16 + it;
    const float* src = z + ((size_t)blk * 64 + r) * D + lane * 8;
    float4 a = ((const float4*)src)[0], b = ((const float4*)src)[1];
    float v[8] = {a.x, a.y, a.z, a.w, b.x, b.y, b.z, b.w};
    uint4 H, L; cvt8(v, H, L);
    const int dc = lane >> 2, gsub = lane & 3;
    const size_t base = (size_t)blk * 8192;
    zpack[base + ((size_t)dc * 8 + gsub) * 64 + r]     = H;
    zpack[base + ((size_t)dc * 8 + 4 + gsub) * 64 + r] = L;
    float ss = 0.f;
    #pragma unroll
    for (int i = 0; i < 8; ++i) ss = fmaf(v[i], v[i], ss);
    #pragma unroll
    for (int mk = 1; mk < 64; mk <<= 1) ss += __shfl_xor(ss, mk);
    if (lane == 0) invn[blk * 64 + r] = 1.0f / fmaxf(sqrtf(ss), 1e-12f);
  }
}

// ---------- pack_c: clusters -> hi/lo bf16 + csq; zero counters ----------
// cpack chunk layout: [dc 16][h 2][g 4][n 1024]
__global__ __launch_bounds__(64) void pack_c(const float* __restrict__ clusters, uint4* __restrict__ cpack,
                                             float* __restrict__ csq, float* __restrict__ lossDelta,
                                             int* __restrict__ flagCnt) {
  const int n = blockIdx.x, t = threadIdx.x;
  const int dc = t >> 2, g = t & 3;
  const float* src = clusters + (size_t)n * D + dc * 32 + g * 8;
  float4 a = ((const float4*)src)[0], b2 = ((const float4*)src)[1];
  float v[8] = {a.x, a.y, a.z, a.w, b2.x, b2.y, b2.z, b2.w};
  uint4 H, L; cvt8(v, H, L);
  cpack[((size_t)(dc * 2 + 0) * 4 + g) * 1024 + n] = H;
  cpack[((size_t)(dc * 2 + 1) * 4 + g) * 1024 + n] = L;
  float sq = 0.f;
  #pragma unroll
  for (int i = 0; i < 8; ++i) sq = fmaf(v[i], v[i], sq);
  #pragma unroll
  for (int m = 32; m >= 1; m >>= 1) sq += __shfl_xor(sq, m);
  if (t == 0) csq[n] = sq;
  if (n == 0 && t == 0) { *lossDelta = 0.f; *flagCnt = 0; }
}

// ---------- main fused kernel ----------
// 256 blocks x 256 thr (4 waves, 2 blocks/CU). Block: 64 rows x all 1024 cols.
// Wave (wr=wid>>1, wc=wid&1): 32 rows x 128 cols per N-tile of 256.
__global__ __launch_bounds__(256, 2) void fused_main(
    const float* __restrict__ z, const char* zpack, const char* __restrict__ cpack,
    const float* __restrict__ csqG, const float* __restrict__ invnG,
    float* out, float* __restrict__ partials,
    float* __restrict__ wsBdot, float* __restrict__ wsInvnt,
    int* __restrict__ flagCnt, int* __restrict__ flagList) {
  __shared__ __align__(16) char Abuf[2][8192];    // [hg 8][r 64] chunks
  __shared__ __align__(16) char Bbuf[2][32768];   // [hg 8][n 256] chunks

  const int tid = threadIdx.x;
  const int wid = tid >> 6;
  const int lane = tid & 63;
  const int h2 = lane >> 5, c5 = lane & 31;
  const int wr = wid >> 1, wc = wid & 1;
  const int blk = blockIdx.x;
  const int row0 = blk * RPB;

  // persistent per-lane state (16 rows each: row = wr*32 + (r&3)+8*(r>>2)+4*h2)
  float runM[16], runS[16], bs[16], bs2[16], invnt[16];
  int bk[16];
  f32x16 acc[4];
  float csqv[4];

  #pragma unroll
  for (int r = 0; r < 16; ++r) {
    runM[r] = -INFINITY; runS[r] = 0.f; bs[r] = INFINITY; bs2[r] = INFINITY; bk[r] = 0;
    const int rloc = (r & 3) + 8 * (r >> 2) + 4 * h2;
    invnt[r] = invnG[row0 + wr * 32 + rloc] * INV_T;
  }
  #pragma unroll
  for (int ct = 0; ct < 4; ++ct) {
    #pragma unroll
    for (int i = 0; i < 16; ++i) acc[ct][i] = 0.f;
    csqv[ct] = csqG[wc * 128 + ct * 32 + c5];   // nt=0
  }

  auto STAGE = [&](int buf, int step) {
    const int nt = step >> 4, dc = step & 15;
    const char* abase = zpack + (((size_t)blk * 16 + dc) * 512) * 16;
    #pragma unroll
    for (int q = 0; q < 2; ++q) {
      const int idx = wid * 2 + q;                 // hg block 0..7
      async_copy16(abase + ((size_t)(idx * 64 + lane)) * 16, Abuf[buf] + idx * 1024);
    }
    #pragma unroll
    for (int q = 0; q < 8; ++q) {
      const int L = wid * 8 + q;
      const int hg = L >> 2, sub = L & 3;
      const int h = hg >> 2, g = hg & 3;
      const char* src = cpack + ((((size_t)(dc * 2 + h) * 4 + g) * 1024) + nt * 256 + sub * 64 + lane) * 16;
      async_copy16(src, Bbuf[buf] + (hg * 256 + sub * 64) * 16);
    }
  };

  STAGE(0, 0);
  __syncthreads();

  for (int t = 0; t < NSTEPS; ++t) {
    const int nt = t >> 4, cur = t & 1;
    if (t + 1 < NSTEPS) STAGE(cur ^ 1, t + 1);

    #pragma unroll
    for (int ks = 0; ks < 2; ++ks) {
      const int g0 = ks * 2 + h2;
      bf16x8 ah = *(const bf16x8*)(Abuf[cur] + ((0 * 4 + g0) * 64 + wr * 32 + c5) * 16);
      bf16x8 al = *(const bf16x8*)(Abuf[cur] + ((1 * 4 + g0) * 64 + wr * 32 + c5) * 16);
      #pragma unroll
      for (int ct = 0; ct < 4; ++ct) {
        bf16x8 bh = *(const bf16x8*)(Bbuf[cur] + ((0 * 4 + g0) * 256 + wc * 128 + ct * 32 + c5) * 16);
        bf16x8 bl = *(const bf16x8*)(Bbuf[cur] + ((1 * 4 + g0) * 256 + wc * 128 + ct * 32 + c5) * 16);
        acc[ct] = __builtin_amdgcn_mfma_f32_32x32x16_bf16(ah, bh, acc[ct], 0, 0, 0);
        acc[ct] = __builtin_amdgcn_mfma_f32_32x32x16_bf16(ah, bl, acc[ct], 0, 0, 0);
        acc[ct] = __builtin_amdgcn_mfma_f32_32x32x16_bf16(al, bh, acc[ct], 0, 0, 0);
      }
    }

    if ((t & 15) == 15) {
      // ---- lane-local per-N-tile epilogue (no shuffles, no barriers) ----
      #pragma unroll
      for (int r = 0; r < 16; ++r) {
        const float l0 = acc[0][r] * invnt[r];
        const float l1 = acc[1][r] * invnt[r];
        const float l2 = acc[2][r] * invnt[r];
        const float l3 = acc[3][r] * invnt[r];
        const float m4 = fmaxf(fmaxf(l0, l1), fmaxf(l2, l3));
        const float nm = fmaxf(runM[r], m4);
        runS[r] = runS[r] * __expf(runM[r] - nm)
                + __expf(l0 - nm) + __expf(l1 - nm) + __expf(l2 - nm) + __expf(l3 - nm);
        runM[r] = nm;
        #pragma unroll
        for (int ct = 0; ct < 4; ++ct) {
          const float s = csqv[ct] - 2.0f * acc[ct][r];
          const int kk = nt * 256 + wc * 128 + ct * 32 + c5;
          if (s < bs[r]) { bs2[r] = bs[r]; bs[r] = s; bk[r] = kk; }
          else           { bs2[r] = fminf(bs2[r], s); }
        }
      }
      #pragma unroll
      for (int ct = 0; ct < 4; ++ct) {
        #pragma unroll
        for (int i = 0; i < 16; ++i) acc[ct][i] = 0.f;
        if (nt < 3) csqv[ct] = csqG[(nt + 1) * 256 + wc * 128 + ct * 32 + c5];
      }
    }
    __syncthreads();
  }

  // ---- final cross-lane merge (once) ----
  float* mrg = (float*)Abuf;   // 2 wc * 64 rows * 5 floats, overlays dead Abuf
  #pragma unroll
  for (int r = 0; r < 16; ++r) {
    float m = runM[r], s = runS[r];
    float b1 = bs[r], b2 = bs2[r]; int k1 = bk[r];
    #pragma unroll
    for (int mk = 1; mk < 32; mk <<= 1) {
      const float om = __shfl_xor(m, mk), os = __shfl_xor(s, mk);
      const float nm = fmaxf(m, om);
      s = s * __expf(m - nm) + os * __expf(om - nm);
      m = nm;
      const float o1 = __shfl_xor(b1, mk); const int ok = __shfl_xor(k1, mk);
      const float o2 = __shfl_xor(b2, mk);
      const bool oth = (o1 < b1) || (o1 == b1 && ok < k1);
      const float loser = oth ? b1 : o1;
      b2 = fminf(loser, fminf(b2, o2));
      if (oth) { b1 = o1; k1 = ok; }
    }
    if (c5 == r) {
      const int row = wr * 32 + (r & 3) + 8 * (r >> 2) + 4 * h2;
      float* q = &mrg[(wc * 64 + row) * 5];
      q[0] = m; q[1] = s; q[2] = b1; q[3] = (float)k1; q[4] = b2;
    }
  }
  __syncthreads();

  if (tid < 64) {
    const int grow = row0 + tid;
    const float* qa = &mrg[(0 * 64 + tid) * 5];
    const float* qb = &mrg[(1 * 64 + tid) * 5];
    const float m0 = qa[0], s0 = qa[1], m1 = qb[0], s1 = qb[1];
    const float nm = fmaxf(m0, m1);
    const float lse = nm + logf(s0 * __expf(m0 - nm) + s1 * __expf(m1 - nm));
    const float b1a = qa[2], b1b = qb[2];
    const int k1a = (int)qa[3], k1b = (int)qb[3];
    const float b2a = qa[4], b2b = qb[4];
    float b1, b2; int k1;
    const bool bsel = (b1b < b1a) || (b1b == b1a && k1b < k1a);
    if (bsel) { b1 = b1b; k1 = k1b; b2 = fminf(b1a, fminf(b2a, b2b)); }
    else      { b1 = b1a; k1 = k1a; b2 = fminf(b1b, fminf(b2a, b2b)); }
    const float bdot = (csqG[k1] - b1) * 0.5f;
    const float invT = invnG[grow] * INV_T;
    out[(size_t)B * D + grow] = (float)k1;
    wsBdot[grow] = bdot;
    wsInvnt[grow] = invT;
    if (b2 - b1 < THETA) { const int pos = atomicAdd(flagCnt, 1); flagList[pos] = grow; }
    float lossr = lse - bdot * invT;
    #pragma unroll
    for (int mk = 1; mk < 64; mk <<= 1) lossr += __shfl_xor(lossr, mk);
    if (tid == 0) partials[blk] = lossr;
  }

  // ---- z_n write (overwrites this block's zpack region; all reads done) ----
  const float4* z4 = (const float4*)(z + (size_t)row0 * D);
  float4* o4 = (float4*)(out + (size_t)row0 * D);
  #pragma unroll
  for (int i = 0; i < 32; ++i) {
    const int e = tid + 256 * i;
    const int r = e >> 7;
    const float inv = invnG[row0 + r];
    float4 v = z4[e];
    v.x *= inv; v.y *= inv; v.z *= inv; v.w *= inv;
    o4[e] = v;
  }
}

// ---------- fixup: exact fp32 re-argmin, one flagged row per block iteration ----------
__global__ __launch_bounds__(256) void fixup(
    const float* __restrict__ z, const float* __restrict__ clusters, const float* __restrict__ csq,
    const int* __restrict__ flagCnt, const int* __restrict__ flagList,
    const float* __restrict__ wsBdot, const float* __restrict__ wsInvnt,
    float* out, float* __restrict__ lossDelta) {
  __shared__ float zrow[D];
  __shared__ float wS[4]; __shared__ int wK[4]; __shared__ float wD[4];
  const int tid = threadIdx.x;
  const int n = *flagCnt;
  for (int f = blockIdx.x; f < n; f += gridDim.x) {
    const int row = flagList[f];
    __syncthreads();
    ((float2*)zrow)[tid] = ((const float2*)(z + (size_t)row * D))[tid];
    __syncthreads();
    float bsv = INFINITY, bd = 0.f; int bkv = 0;
    #pragma unroll
    for (int kk = 0; kk < 4; ++kk) {
      const int k = tid * 4 + kk;
      const float4* c4 = (const float4*)(clusters + (size_t)k * D);
      float dot = 0.f;
      #pragma unroll 16
      for (int i = 0; i < 128; ++i) {
        const float4 cv = c4[i]; const float4 zv = ((const float4*)zrow)[i];
        dot = fmaf(cv.x, zv.x, dot); dot = fmaf(cv.y, zv.y, dot);
        dot = fmaf(cv.z, zv.z, dot); dot = fmaf(cv.w, zv.w, dot);
      }
      const float s = csq[k] - 2.f * dot;
      if (s < bsv) { bsv = s; bkv = k; bd = dot; }
    }
    #pragma unroll
    for (int mk = 1; mk < 64; mk <<= 1) {
      const float os = __shfl_xor(bsv, mk); const int ok = __shfl_xor(bkv, mk);
      const float od = __shfl_xor(bd, mk);
      if (os < bsv || (os == bsv && ok < bkv)) { bsv = os; bkv = ok; bd = od; }
    }
    if ((tid & 63) == 0) { wS[tid >> 6] = bsv; wK[tid >> 6] = bkv; wD[tid >> 6] = bd; }
    __syncthreads();
    if (tid == 0) {
      float fs = wS[0]; int fk = wK[0]; float fd = wD[0];
      for (int w = 1; w < 4; ++w)
        if (wS[w] < fs || (wS[w] == fs && wK[w] < fk)) { fs = wS[w]; fk = wK[w]; fd = wD[w]; }
      const int oldk = (int)out[(size_t)B * D + row];
      if (fk != oldk) {
        out[(size_t)B * D + row] = (float)fk;
        atomicAdd(lossDelta, (wsBdot[row] - fd) * wsInvnt[row]);
      }
    }
    __syncthreads();
  }
}

// ---------- final loss reduction (256 partials) ----------
__global__ __launch_bounds__(256) void loss_final(const float* __restrict__ partials,
                                                  const float* __restrict__ lossDelta,
                                                  float* __restrict__ out) {
  const int t = threadIdx.x;
  float s = partials[t];
  #pragma unroll
  for (int mk = 1; mk < 64; mk <<= 1) s += __shfl_xor(s, mk);
  __shared__ float w[4];
  if ((t & 63) == 0) w[t >> 6] = s;
  __syncthreads();
  if (t == 0) out[(size_t)B * D + B] = (w[0] + w[1] + w[2] + w[3] + *lossDelta) * (1.0f / (float)B);
}

extern "C" void kernel_launch(void* const* d_in, const int* in_sizes, int n_in,
                              void* d_out, int out_size, void* d_ws, size_t ws_size,
                              hipStream_t stream) {
  const float* z        = (const float*)d_in[0];
  const float* clusters = (const float*)d_in[1];
  float* out = (float*)d_out;

  // ws layout (~2.3 MB)
  uint4* cpack     = (uint4*)d_ws;                      // 2 MB
  float* csq       = (float*)((char*)d_ws + (2u << 20)); // 1024 f
  float* partials  = csq + 1024;                         // 256 f
  float* invn      = partials + 256;                     // 16384 f
  float* wsBdot    = invn + B;                           // 16384 f
  float* wsInvnt   = wsBdot + B;                         // 16384 f
  float* lossDelta = wsInvnt + B;                        // 1 f
  int*   flagCnt   = (int*)(lossDelta + 1);              // 1 i
  int*   flagList  = flagCnt + 1;                        // 16384 i

  pack_c<<<K, 64, 0, stream>>>(clusters, cpack, csq, lossDelta, flagCnt);
  pack_z<<<B / RPB, 256, 0, stream>>>(z, (uint4*)d_out, invn);
  fused_main<<<B / RPB, 256, 0, stream>>>(z, (const char*)d_out, (const char*)cpack,
                                          csq, invn, out, partials, wsBdot, wsInvnt,
                                          flagCnt, flagList);
  fixup<<<64, 256, 0, stream>>>(z, clusters, csq, flagCnt, flagList, wsBdot, wsInvnt,
                                out, lossDelta);
  loss_final<<<1, 256, 0, stream>>>(partials, lossDelta, out);
}

// Round 4
// 228.458 us; speedup vs baseline: 4.8391x; 1.5747x over previous
//
#include <hip/hip_runtime.h>
#include <hip/hip_bf16.h>
#include <math.h>

#define B 16384
#define K 1024
#define D 512
#define INV_T 14.285714285714286f   // 1/0.07
#define THETA 0.01f
#define RPB 32                      // rows per main block
#define NSTEPS 64                   // 4 nt * 16 dc

typedef __attribute__((ext_vector_type(8))) short bf16x8;
typedef __attribute__((ext_vector_type(16))) float f32x16;
typedef unsigned long long u64;

typedef const __attribute__((address_space(1))) void* gas_ptr;
typedef __attribute__((address_space(3))) void* las_ptr;

__device__ __forceinline__ void async_copy16(const void* g, void* l) {
  __builtin_amdgcn_global_load_lds((gas_ptr)g, (las_ptr)l, 16, 0, 0);
}

// hi/lo bf16 split via native casts (compiler emits cvt_pk pairs)
__device__ __forceinline__ void cvt8(const float* v, uint4& H, uint4& L) {
  unsigned h[8], l[8];
  #pragma unroll
  for (int i = 0; i < 8; ++i) {
    __hip_bfloat16 hb = __float2bfloat16(v[i]);       // RNE
    float lo = v[i] - __bfloat162float(hb);
    __hip_bfloat16 lb = __float2bfloat16(lo);
    h[i] = __hip_bfloat16_raw(hb).x;
    l[i] = __hip_bfloat16_raw(lb).x;
  }
  H = make_uint4(h[0] | (h[1] << 16), h[2] | (h[3] << 16), h[4] | (h[5] << 16), h[6] | (h[7] << 16));
  L = make_uint4(l[0] | (l[1] << 16), l[2] | (l[3] << 16), l[4] | (l[5] << 16), l[6] | (l[7] << 16));
}

__device__ __forceinline__ u64 packSK(float s, int k) {
  unsigned u = __float_as_uint(s + 100000.0f);        // s > -1e5 always -> positive, monotone
  return ((u64)u << 32) | (unsigned)k;
}

// ---------- pack_z: z -> hi/lo bf16 tiled into OUT region + invn ----------
// zpack chunks (16B): idx = blk*4096 + dc*256 + hg*32 + r   (hg = h*4+g)
// chunk = bf16x8 of z[blk*32+r][dc*32+g*8 .. +8]
__global__ __launch_bounds__(256) void pack_z(const float* __restrict__ z,
                                              uint4* __restrict__ zpack,
                                              float* __restrict__ invn) {
  const int blk = blockIdx.x;
  const int wid = threadIdx.x >> 6, lane = threadIdx.x & 63;
  const int dc = lane >> 2, g = lane & 3;
  #pragma unroll
  for (int it = 0; it < 8; ++it) {
    const int r = wid * 8 + it;
    const float* src = z + ((size_t)blk * RPB + r) * D + lane * 8;
    float4 a = ((const float4*)src)[0], b = ((const float4*)src)[1];
    float v[8] = {a.x, a.y, a.z, a.w, b.x, b.y, b.z, b.w};
    uint4 H, L; cvt8(v, H, L);
    const size_t base = (size_t)blk * 4096 + dc * 256;
    zpack[base + g * 32 + r]       = H;
    zpack[base + (4 + g) * 32 + r] = L;
    float ss = 0.f;
    #pragma unroll
    for (int i = 0; i < 8; ++i) ss = fmaf(v[i], v[i], ss);
    #pragma unroll
    for (int mk = 1; mk < 64; mk <<= 1) ss += __shfl_xor(ss, mk);
    if (lane == 0) invn[blk * RPB + r] = 1.0f / fmaxf(sqrtf(ss), 1e-12f);
  }
}

// ---------- pack_c: clusters -> hi/lo bf16 + csq ----------
// cpack chunks: idx = ((dc*4 + nt)*8 + hg)*256 + c   (n = nt*256 + c)
__global__ __launch_bounds__(64) void pack_c(const float* __restrict__ clusters, uint4* __restrict__ cpack,
                                             float* __restrict__ csq, int* __restrict__ flagCnt) {
  const int n = blockIdx.x, t = threadIdx.x;
  const int dc = t >> 2, g = t & 3;
  const int nt = n >> 8, c = n & 255;
  const float* src = clusters + (size_t)n * D + dc * 32 + g * 8;
  float4 a = ((const float4*)src)[0], b2 = ((const float4*)src)[1];
  float v[8] = {a.x, a.y, a.z, a.w, b2.x, b2.y, b2.z, b2.w};
  uint4 H, L; cvt8(v, H, L);
  cpack[((size_t)(dc * 4 + nt) * 8 + g) * 256 + c]     = H;
  cpack[((size_t)(dc * 4 + nt) * 8 + 4 + g) * 256 + c] = L;
  float sq = 0.f;
  #pragma unroll
  for (int i = 0; i < 8; ++i) sq = fmaf(v[i], v[i], sq);
  #pragma unroll
  for (int m = 32; m >= 1; m >>= 1) sq += __shfl_xor(sq, m);
  if (t == 0) csq[n] = sq;
  if (n == 0 && t == 0) *flagCnt = 0;
}

// ---------- main fused kernel ----------
// 512 blocks x 256 thr (4 waves, 2 blocks/CU). Block: 32 rows x all 1024 cols.
// Wave wc = wid: 32 rows x 64 cols of the 256-col N-tile (ct 0..1).
__global__ __launch_bounds__(256, 2) void fused_main(
    const float* __restrict__ z, const char* zpack, const char* __restrict__ cpack,
    const float* __restrict__ csqG, const float* __restrict__ invnG,
    float* out, float* __restrict__ partials,
    float* __restrict__ wsBdot, float* __restrict__ wsInvnt,
    int* __restrict__ flagCnt, int* __restrict__ flagList, u64* __restrict__ wsBest) {
  __shared__ __align__(16) char Abuf[2][4096];    // [hg 8][r 32] chunks
  __shared__ __align__(16) char Bbuf[2][32768];   // [hg 8][c 256] chunks

  const int tid = threadIdx.x;
  const int wid = tid >> 6;         // = wc
  const int lane = tid & 63;
  const int h2 = lane >> 5, c5 = lane & 31;
  const int blk = blockIdx.x;
  const int row0 = blk * RPB;
  const char* zpB = zpack + (size_t)blk * 65536;

  float runM[16], runS[16], bs[16], bs2[16], invnt[16];
  int bk[16];
  f32x16 acc[2];

  #pragma unroll
  for (int r = 0; r < 16; ++r) {
    runM[r] = -INFINITY; runS[r] = 0.f; bs[r] = INFINITY; bs2[r] = INFINITY; bk[r] = 0;
    const int rloc = (r & 3) + 8 * (r >> 2) + 4 * h2;
    invnt[r] = invnG[row0 + rloc] * INV_T;
  }
  #pragma unroll
  for (int i = 0; i < 16; ++i) { acc[0][i] = 0.f; acc[1][i] = 0.f; }

  auto STAGE = [&](int buf, int step) {
    const int nt = step >> 4, dc = step & 15;
    // A: 256 chunks, 1 load per wave
    async_copy16(zpB + ((size_t)(dc * 256 + wid * 64 + lane)) * 16, Abuf[buf] + wid * 1024);
    // B: 2048 chunks (32KB), 8 loads per wave, linear src
    const char* bbase = cpack + ((size_t)(dc * 4 + nt)) * 32768;
    #pragma unroll
    for (int q = 0; q < 8; ++q) {
      const int L = wid * 8 + q;
      async_copy16(bbase + ((size_t)(L * 64 + lane)) * 16, Bbuf[buf] + L * 1024);
    }
  };

  STAGE(0, 0);
  __syncthreads();

  for (int t = 0; t < NSTEPS; ++t) {
    const int nt = t >> 4, cur = t & 1;
    if (t + 1 < NSTEPS) STAGE(cur ^ 1, t + 1);

    #pragma unroll
    for (int ks = 0; ks < 2; ++ks) {
      const int g0 = ks * 2 + h2;
      bf16x8 ah = *(const bf16x8*)(Abuf[cur] + (g0 * 32 + c5) * 16);
      bf16x8 al = *(const bf16x8*)(Abuf[cur] + ((4 + g0) * 32 + c5) * 16);
      #pragma unroll
      for (int ct = 0; ct < 2; ++ct) {
        const int col = wid * 64 + ct * 32 + c5;
        bf16x8 bh = *(const bf16x8*)(Bbuf[cur] + (g0 * 256 + col) * 16);
        bf16x8 bl = *(const bf16x8*)(Bbuf[cur] + ((4 + g0) * 256 + col) * 16);
        acc[ct] = __builtin_amdgcn_mfma_f32_32x32x16_bf16(ah, bh, acc[ct], 0, 0, 0);
        acc[ct] = __builtin_amdgcn_mfma_f32_32x32x16_bf16(ah, bl, acc[ct], 0, 0, 0);
        acc[ct] = __builtin_amdgcn_mfma_f32_32x32x16_bf16(al, bh, acc[ct], 0, 0, 0);
      }
    }

    if ((t & 15) == 15) {
      // ---- lane-local per-N-tile epilogue ----
      const int kk0 = nt * 256 + wid * 64 + c5;
      const float cs0 = csqG[kk0], cs1 = csqG[kk0 + 32];
      #pragma unroll
      for (int r = 0; r < 16; ++r) {
        const float l0 = acc[0][r] * invnt[r];
        const float l1 = acc[1][r] * invnt[r];
        const float nm = fmaxf(runM[r], fmaxf(l0, l1));
        runS[r] = runS[r] * __expf(runM[r] - nm) + __expf(l0 - nm) + __expf(l1 - nm);
        runM[r] = nm;
        const float s0 = cs0 - 2.0f * acc[0][r];
        const float s1 = cs1 - 2.0f * acc[1][r];
        if (s0 < bs[r]) { bs2[r] = bs[r]; bs[r] = s0; bk[r] = kk0; }
        else            { bs2[r] = fminf(bs2[r], s0); }
        if (s1 < bs[r]) { bs2[r] = bs[r]; bs[r] = s1; bk[r] = kk0 + 32; }
        else            { bs2[r] = fminf(bs2[r], s1); }
        acc[0][r] = 0.f; acc[1][r] = 0.f;
      }
    }
    __syncthreads();
  }

  // ---- final cross-lane merge ----
  float* mrg = (float*)Abuf;   // 4 waves * 32 rows * 5 floats = 2.5KB
  #pragma unroll
  for (int r = 0; r < 16; ++r) {
    float m = runM[r], s = runS[r];
    float b1 = bs[r], b2 = bs2[r]; int k1 = bk[r];
    #pragma unroll
    for (int mk = 1; mk < 32; mk <<= 1) {
      const float om = __shfl_xor(m, mk), os = __shfl_xor(s, mk);
      const float nm = fmaxf(m, om);
      s = s * __expf(m - nm) + os * __expf(om - nm);
      m = nm;
      const float o1 = __shfl_xor(b1, mk); const int ok = __shfl_xor(k1, mk);
      const float o2 = __shfl_xor(b2, mk);
      const bool oth = (o1 < b1) || (o1 == b1 && ok < k1);
      const float loser = oth ? b1 : o1;
      b2 = fminf(loser, fminf(b2, o2));
      if (oth) { b1 = o1; k1 = ok; }
    }
    if (c5 == r) {
      const int row = (r & 3) + 8 * (r >> 2) + 4 * h2;
      float* q = &mrg[(wid * 32 + row) * 5];
      q[0] = m; q[1] = s; q[2] = b1; q[3] = (float)k1; q[4] = b2;
    }
  }
  __syncthreads();

  if (tid < 32) {
    const int grow = row0 + tid;
    float rm = -INFINITY, rs = 0.f, r1 = INFINITY, r2 = INFINITY;
    int rk = 0;
    #pragma unroll
    for (int w = 0; w < 4; ++w) {
      const float* q = &mrg[(w * 32 + tid) * 5];
      const float tm = q[0], ts = q[1], t1 = q[2]; const int tk = (int)q[3]; const float t2 = q[4];
      const float nm = fmaxf(rm, tm);
      rs = rs * __expf(rm - nm) + ts * __expf(tm - nm);
      rm = nm;
      const bool oth = (t1 < r1) || (t1 == r1 && tk < rk);
      const float loser = oth ? r1 : t1;
      r2 = fminf(loser, fminf(r2, t2));
      if (oth) { r1 = t1; rk = tk; }
    }
    const float lse = rm + logf(rs);
    const float bdot = (csqG[rk] - r1) * 0.5f;
    const float invT = invnG[grow] * INV_T;
    out[(size_t)B * D + grow] = (float)rk;
    wsBdot[grow] = bdot;
    wsInvnt[grow] = invT;
    if (r2 - r1 < THETA) {
      const int pos = atomicAdd(flagCnt, 1);
      flagList[pos] = grow;
      wsBest[pos] = ~0ull;
    }
    float lossr = lse - bdot * invT;
    #pragma unroll
    for (int mk = 1; mk < 32; mk <<= 1) lossr += __shfl_xor(lossr, mk);
    if (tid == 0) partials[blk] = lossr;
  }

  // ---- z_n write (overwrites this block's zpack slice; reads done) ----
  const float4* z4 = (const float4*)(z + (size_t)row0 * D);
  float4* o4 = (float4*)(out + (size_t)row0 * D);
  #pragma unroll
  for (int i = 0; i < 16; ++i) {
    const int e = tid + 256 * i;
    const int r = e >> 7;
    const float inv = invnG[row0 + r];
    float4 v = z4[e];
    v.x *= inv; v.y *= inv; v.z *= inv; v.w *= inv;
    o4[e] = v;
  }
}

// ---------- fixup: exact fp32 re-argmin; 8 blocks per flagged row ----------
__global__ __launch_bounds__(256) void fixup(
    const float* __restrict__ z, const float* __restrict__ clusters, const float* __restrict__ csq,
    const int* __restrict__ flagCnt, const int* __restrict__ flagList, u64* __restrict__ wsBest) {
  __shared__ float zrow[D];
  __shared__ float wS[4]; __shared__ int wK[4];
  const int tid = threadIdx.x;
  const int n = *flagCnt;
  const int chunk = blockIdx.x & 7;
  for (int f = blockIdx.x >> 3; f < n; f += 64) {
    const int row = flagList[f];
    __syncthreads();
    ((float2*)zrow)[tid] = ((const float2*)(z + (size_t)row * D))[tid];
    __syncthreads();
    const int k = chunk * 128 + (tid >> 1), half = tid & 1;
    const float4* c4 = (const float4*)(clusters + (size_t)k * D + half * 256);
    const float4* z4 = (const float4*)(zrow + half * 256);
    float dot = 0.f;
    #pragma unroll 16
    for (int i = 0; i < 64; ++i) {
      const float4 cv = c4[i]; const float4 zv = z4[i];
      dot = fmaf(cv.x, zv.x, dot); dot = fmaf(cv.y, zv.y, dot);
      dot = fmaf(cv.z, zv.z, dot); dot = fmaf(cv.w, zv.w, dot);
    }
    dot += __shfl_xor(dot, 1);
    float s = csq[k] - 2.f * dot;
    int bkv = k;
    #pragma unroll
    for (int mk = 2; mk < 64; mk <<= 1) {
      const float os = __shfl_xor(s, mk); const int ok = __shfl_xor(bkv, mk);
      if (os < s || (os == s && ok < bkv)) { s = os; bkv = ok; }
    }
    if ((tid & 63) == 0) { wS[tid >> 6] = s; wK[tid >> 6] = bkv; }
    __syncthreads();
    if (tid == 0) {
      float fs = wS[0]; int fk = wK[0];
      for (int w = 1; w < 4; ++w)
        if (wS[w] < fs || (wS[w] == fs && wK[w] < fk)) { fs = wS[w]; fk = wK[w]; }
      atomicMin(&wsBest[f], packSK(fs, fk));
    }
    __syncthreads();
  }
}

// ---------- final loss reduction + flagged-row resolution ----------
__global__ __launch_bounds__(256) void loss_final(
    const float* __restrict__ partials, const float* __restrict__ csq,
    const int* __restrict__ flagCnt, const int* __restrict__ flagList,
    const u64* __restrict__ wsBest, const float* __restrict__ wsBdot,
    const float* __restrict__ wsInvnt, float* out) {
  const int t = threadIdx.x;
  float s = partials[t] + partials[t + 256];
  const int n = *flagCnt;
  for (int f = t; f < n; f += 256) {
    const int row = flagList[f];
    const u64 v = wsBest[f];
    const int kN = (int)(unsigned)(v & 0xffffffffu);
    const float sN = __uint_as_float((unsigned)(v >> 32)) - 100000.0f;
    const int kO = (int)out[(size_t)B * D + row];
    if (kN != kO) {
      out[(size_t)B * D + row] = (float)kN;
      const float bdN = (csq[kN] - sN) * 0.5f;
      s += (wsBdot[row] - bdN) * wsInvnt[row];
    }
  }
  #pragma unroll
  for (int mk = 1; mk < 64; mk <<= 1) s += __shfl_xor(s, mk);
  __shared__ float w[4];
  if ((t & 63) == 0) w[t >> 6] = s;
  __syncthreads();
  if (t == 0) out[(size_t)B * D + B] = (w[0] + w[1] + w[2] + w[3]) * (1.0f / (float)B);
}

extern "C" void kernel_launch(void* const* d_in, const int* in_sizes, int n_in,
                              void* d_out, int out_size, void* d_ws, size_t ws_size,
                              hipStream_t stream) {
  const float* z        = (const float*)d_in[0];
  const float* clusters = (const float*)d_in[1];
  float* out = (float*)d_out;

  // ws layout (~2.45 MB)
  char* wsb = (char*)d_ws;
  uint4* cpack     = (uint4*)wsb;                          // 2 MB
  u64*   wsBest    = (u64*)(wsb + (2u << 20));             // 128 KB (8-aligned)
  float* csq       = (float*)(wsb + (2u << 20) + (128u << 10)); // 1024 f
  float* partials  = csq + 1024;                           // 512 f
  float* invn      = partials + 512;                       // 16384 f
  float* wsBdot    = invn + B;                             // 16384 f
  float* wsInvnt   = wsBdot + B;                           // 16384 f
  int*   flagCnt   = (int*)(wsInvnt + B);                  // 1 i
  int*   flagList  = flagCnt + 1;                          // 16384 i

  pack_c<<<K, 64, 0, stream>>>(clusters, cpack, csq, flagCnt);
  pack_z<<<B / RPB, 256, 0, stream>>>(z, (uint4*)d_out, invn);
  fused_main<<<B / RPB, 256, 0, stream>>>(z, (const char*)d_out, (const char*)cpack,
                                          csq, invn, out, partials, wsBdot, wsInvnt,
                                          flagCnt, flagList, wsBest);
  fixup<<<512, 256, 0, stream>>>(z, clusters, csq, flagCnt, flagList, wsBest);
  loss_final<<<1, 256, 0, stream>>>(partials, csq, flagCnt, flagList, wsBest,
                                    wsBdot, wsInvnt, out);
}